// Round 4
// baseline (7445.399 us; speedup 1.0000x reference)
//
#include <hip/hip_runtime.h>
#include <math.h>

// Problem constants
#define B_   16
#define C_   128
#define H_   32
#define W_   32
#define D_   64
#define K_   8192
#define HW_  (H_*W_)       // 1024
#define N_   (B_*HW_)      // 16384

// MFMA sweep config
#define CS      16         // code splits (grid.y)
#define CPB     (K_/CS)    // 512 codes per block
#define CHUNK   128        // codes per LDS chunk
#define ROWS_PB 256        // rows per block (4 waves x 64 rows)
#define MARGIN  0.5f       // >> bf16 score error bound (~0.01)
#define CAND_CAP 32

typedef short v8s __attribute__((ext_vector_type(8)));
typedef float v4f __attribute__((ext_vector_type(4)));

__device__ __forceinline__ short f2bf(float f) {   // RNE fp32 -> bf16
    union { float fv; unsigned u; } cv; cv.fv = f;
    unsigned u = cv.u;
    unsigned rnd = ((u >> 16) & 1u) + 0x7fffu;
    return (short)((u + rnd) >> 16);
}

// Exact fp32 score, bit-identical to the R2 kernel that matched the reference:
// even/odd d4 interleave into two accumulators, then (sa+sb) - hn.
__device__ __forceinline__ float exact_score(const float4* __restrict__ zr,
                                             const float* __restrict__ embed,
                                             float h, int k)
{
    const float4* ep = (const float4*)(embed + (size_t)k * D_);
    float sa = 0.f, sb = 0.f;
    #pragma unroll
    for (int d4 = 0; d4 < 16; d4 += 2) {
        float4 ea = ep[d4], eb = ep[d4 + 1];
        sa += ea.x*zr[d4].x + ea.y*zr[d4].y + ea.z*zr[d4].z + ea.w*zr[d4].w;
        sb += eb.x*zr[d4+1].x + eb.y*zr[d4+1].y + eb.z*zr[d4+1].z + eb.w*zr[d4+1].w;
    }
    return (sa + sb) - h;
}

// ---------------- Kernel 1: 1x1 conv + BN -> z_e [N_, 64] ----------------
__global__ __launch_bounds__(256) void k_proj(
    const float* __restrict__ z, const float* __restrict__ pw,
    const float* __restrict__ pb, const float* __restrict__ gamma,
    const float* __restrict__ beta, const float* __restrict__ rmean,
    const float* __restrict__ rvar, float* __restrict__ ze)
{
    __shared__ float zt[64][132];
    __shared__ float wl[64][132];
    const int tid = threadIdx.x;
    const int n0  = blockIdx.x * 64;
    const int b   = n0 / HW_;
    const int hw0 = n0 % HW_;
    const float* zb = z + (size_t)b * C_ * HW_ + hw0;

    #pragma unroll
    for (int it = 0; it < 32; ++it) {
        int flat = tid + 256 * it;
        int c = flat >> 6, p = flat & 63;
        zt[p][c] = zb[c * HW_ + p];
    }
    #pragma unroll
    for (int it = 0; it < 32; ++it) {
        int flat = tid + 256 * it;
        int d = flat >> 7, c = flat & 127;
        wl[d][c] = pw[d * C_ + c];
    }
    __syncthreads();

    const int tp = tid & 15;
    const int td = tid >> 4;
    float acc[4][4] = {};
    #pragma unroll
    for (int c4 = 0; c4 < 32; ++c4) {
        float4 zv[4], wv[4];
        #pragma unroll
        for (int i = 0; i < 4; ++i) zv[i] = *(const float4*)&zt[4*tp + i][4*c4];
        #pragma unroll
        for (int j = 0; j < 4; ++j) wv[j] = *(const float4*)&wl[4*td + j][4*c4];
        #pragma unroll
        for (int i = 0; i < 4; ++i)
            #pragma unroll
            for (int j = 0; j < 4; ++j)
                acc[i][j] += zv[i].x*wv[j].x + zv[i].y*wv[j].y
                           + zv[i].z*wv[j].z + zv[i].w*wv[j].w;
    }

    float sc[4], bi[4];
    #pragma unroll
    for (int j = 0; j < 4; ++j) {
        int d = 4*td + j;
        float s = gamma[d] / sqrtf(rvar[d] + 1e-5f);
        sc[j] = s;
        bi[j] = pb[d] * s + beta[d] - rmean[d] * s;
    }
    #pragma unroll
    for (int i = 0; i < 4; ++i) {
        int n = n0 + 4*tp + i;
        float4 o;
        o.x = acc[i][0]*sc[0] + bi[0];
        o.y = acc[i][1]*sc[1] + bi[1];
        o.z = acc[i][2]*sc[2] + bi[2];
        o.w = acc[i][3]*sc[3] + bi[3];
        *(float4*)&ze[(size_t)n * D_ + 4*td] = o;
    }
}

// ---------------- Kernel 2: hn[k] = 0.5 * ||embed_k||^2 ----------------
__global__ __launch_bounds__(256) void k_hnorm(const float* __restrict__ e,
                                               float* __restrict__ hn)
{
    int t = blockIdx.x * 256 + threadIdx.x;
    float4 v = ((const float4*)e)[t];
    float s = v.x*v.x + v.y*v.y + v.z*v.z + v.w*v.w;
    s += __shfl_xor(s, 1);
    s += __shfl_xor(s, 2);
    s += __shfl_xor(s, 4);
    s += __shfl_xor(s, 8);
    if ((threadIdx.x & 15) == 0) hn[t >> 4] = 0.5f * s;
}

// ---------------- Kernel 3: MFMA bf16 sweep ----------------
template<bool PUSH>
__global__ __launch_bounds__(256) void k_sweep(
    const float* __restrict__ ze, const float* __restrict__ embed,
    const float* __restrict__ hn, float* __restrict__ pbest,
    const float* __restrict__ Vm, int* __restrict__ cnt,
    int* __restrict__ cand)
{
    __shared__ short eb[CHUNK * 72];   // 144B stride/code: b128 reads 2-way only
    __shared__ float hl[CHUNK];
    const int tid  = threadIdx.x;
    const int lane = tid & 63;
    const int wv   = tid >> 6;
    const int quad = lane >> 4;
    const int l15  = lane & 15;
    const int rowBase = blockIdx.x * ROWS_PB + wv * 64;
    const int code0   = blockIdx.y * CPB;

    // A fragments: 4 row-tiles x 2 k-frags; A[m=l15][k=quad*8+j] (+32 for f=1)
    v8s A[4][2];
    #pragma unroll
    for (int rt = 0; rt < 4; ++rt) {
        const float* zp = ze + (size_t)(rowBase + rt*16 + l15) * D_ + quad*8;
        #pragma unroll
        for (int f = 0; f < 2; ++f) {
            v8s a;
            #pragma unroll
            for (int j = 0; j < 8; ++j) a[j] = f2bf(zp[f*32 + j]);
            A[rt][f] = a;
        }
    }

    float best[4][4];
    float vm[4][4];
    if (PUSH) {
        #pragma unroll
        for (int rt = 0; rt < 4; ++rt)
            #pragma unroll
            for (int r = 0; r < 4; ++r)
                vm[rt][r] = Vm[rowBase + rt*16 + quad*4 + r];
    } else {
        #pragma unroll
        for (int rt = 0; rt < 4; ++rt)
            #pragma unroll
            for (int r = 0; r < 4; ++r) best[rt][r] = -INFINITY;
    }

    for (int ch = 0; ch < CPB / CHUNK; ++ch) {
        const int c0 = code0 + ch * CHUNK;
        __syncthreads();
        #pragma unroll
        for (int i = 0; i < 8; ++i) {
            int idx = tid + 256 * i;           // float4 units
            int c = idx >> 4, p = idx & 15;
            float4 v = ((const float4*)embed)[(size_t)(c0 + c) * 16 + p];
            short4 s4;
            s4.x = f2bf(v.x); s4.y = f2bf(v.y); s4.z = f2bf(v.z); s4.w = f2bf(v.w);
            *(short4*)&eb[c * 72 + p * 4] = s4;
        }
        if (tid < CHUNK) hl[tid] = hn[c0 + tid];
        __syncthreads();

        #pragma unroll
        for (int t = 0; t < CHUNK / 16; ++t) {
            const int cc = t * 16 + l15;
            v8s B0 = *(const v8s*)&eb[cc * 72 + quad * 8];        // d 0..31
            v8s B1 = *(const v8s*)&eb[cc * 72 + 32 + quad * 8];   // d 32..63
            const float mh = -hl[t * 16 + l15];
            #pragma unroll
            for (int rt = 0; rt < 4; ++rt) {
                v4f c = {mh, mh, mh, mh};
                c = __builtin_amdgcn_mfma_f32_16x16x32_bf16(A[rt][0], B0, c, 0, 0, 0);
                c = __builtin_amdgcn_mfma_f32_16x16x32_bf16(A[rt][1], B1, c, 0, 0, 0);
                if (!PUSH) {
                    #pragma unroll
                    for (int r = 0; r < 4; ++r) best[rt][r] = fmaxf(best[rt][r], c[r]);
                } else {
                    const int code = c0 + t * 16 + l15;
                    #pragma unroll
                    for (int r = 0; r < 4; ++r) {
                        if (c[r] > vm[rt][r]) {
                            int row = rowBase + rt*16 + quad*4 + r;
                            int s = atomicAdd(&cnt[row], 1);
                            if (s < CAND_CAP) cand[row * CAND_CAP + s] = code;
                        }
                    }
                }
            }
        }
    }

    if (!PUSH) {
        #pragma unroll
        for (int rt = 0; rt < 4; ++rt)
            #pragma unroll
            for (int r = 0; r < 4; ++r) {
                float v = best[rt][r];
                v = fmaxf(v, __shfl_xor(v, 1));
                v = fmaxf(v, __shfl_xor(v, 2));
                v = fmaxf(v, __shfl_xor(v, 4));
                v = fmaxf(v, __shfl_xor(v, 8));
                if (l15 == 0)
                    pbest[(size_t)blockIdx.y * N_ + rowBase + rt*16 + quad*4 + r] = v;
            }
    }
}

// ---------------- Kernel 4: combine splits -> threshold, zero counters ----
__global__ __launch_bounds__(256) void k_comb(const float* __restrict__ pbest,
                                              float* __restrict__ Vm,
                                              int* __restrict__ cnt)
{
    int n = blockIdx.x * 256 + threadIdx.x;
    float v = -INFINITY;
    #pragma unroll
    for (int s = 0; s < CS; ++s) v = fmaxf(v, pbest[(size_t)s * N_ + n]);
    Vm[n] = v - MARGIN;
    cnt[n] = 0;
}

// ---------------- Kernel 5: exact fp32 rescore + outputs ----------------
__global__ __launch_bounds__(256) void k_pick(
    const int* __restrict__ cnt, const int* __restrict__ cand,
    const float* __restrict__ embed, const float* __restrict__ hn,
    const float* __restrict__ ze, float* __restrict__ out0,
    float* __restrict__ outIdx, float* __restrict__ bsum)
{
    const int tid = threadIdx.x;
    const int n   = blockIdx.x * 256 + tid;

    float4 zr[16];
    const float4* zp = (const float4*)(ze + (size_t)n * D_);
    #pragma unroll
    for (int i = 0; i < 16; ++i) zr[i] = zp[i];

    const int m = cnt[n];
    float best = -INFINITY;
    int   bidx = 0x7fffffff;
    if (m > CAND_CAP) {
        // overflow fallback: full exact scan, ascending k (replicates R2 exactly)
        for (int k = 0; k < K_; ++k) {
            float s = exact_score(zr, embed, hn[k], k);
            if (s > best) { best = s; bidx = k; }
        }
    } else {
        for (int i = 0; i < m; ++i) {
            int k = cand[n * CAND_CAP + i];
            float s = exact_score(zr, embed, hn[k], k);
            // candidates arrive unordered: (s==best && k<bidx) == ascending strict->
            if (s > best || (s == best && k < bidx)) { best = s; bidx = k; }
        }
    }
    if (bidx == 0x7fffffff) bidx = 0;   // unreachable safety
    outIdx[n] = (float)bidx;

    const float4* eq = (const float4*)(embed + (size_t)bidx * D_);
    const int b = n >> 10, hw = n & 1023;
    float* o = out0 + (size_t)b * (D_ * HW_) + hw;

    float local = 0.f;
    #pragma unroll
    for (int d4 = 0; d4 < 16; ++d4) {
        float4 e = eq[d4], zv = zr[d4];
        float dx = e.x - zv.x, dy = e.y - zv.y, dz = e.z - zv.z, dw = e.w - zv.w;
        local += dx*dx + dy*dy + dz*dz + dw*dw;
        o[(4*d4 + 0) * HW_] = e.x;
        o[(4*d4 + 1) * HW_] = e.y;
        o[(4*d4 + 2) * HW_] = e.z;
        o[(4*d4 + 3) * HW_] = e.w;
    }

    __shared__ float red[256];
    red[tid] = local;
    __syncthreads();
    for (int s = 128; s > 0; s >>= 1) {
        if (tid < s) red[tid] += red[tid + s];
        __syncthreads();
    }
    if (tid == 0) bsum[blockIdx.x] = red[0];
}

// ---------------- Kernel 6: diff scalar ----------------
__global__ void k_diff(const float* __restrict__ bsum, float* __restrict__ outd)
{
    float s = bsum[threadIdx.x];
    s += __shfl_xor(s, 1);
    s += __shfl_xor(s, 2);
    s += __shfl_xor(s, 4);
    s += __shfl_xor(s, 8);
    s += __shfl_xor(s, 16);
    s += __shfl_xor(s, 32);
    if (threadIdx.x == 0) *outd = s * (12.5f / (float)(N_ * D_));
}

extern "C" void kernel_launch(void* const* d_in, const int* in_sizes, int n_in,
                              void* d_out, int out_size, void* d_ws, size_t ws_size,
                              hipStream_t stream)
{
    const float* z     = (const float*)d_in[0];
    const float* pw    = (const float*)d_in[1];
    const float* pb    = (const float*)d_in[2];
    const float* gamma = (const float*)d_in[3];
    const float* beta  = (const float*)d_in[4];
    const float* rmean = (const float*)d_in[5];
    const float* rvar  = (const float*)d_in[6];
    const float* embed = (const float*)d_in[7];

    float* out = (float*)d_out;
    float* out0    = out;                     // [B,D,H,W]
    float* outDiff = out + (size_t)N_ * D_;   // scalar
    float* outIdx  = outDiff + 1;             // [B,H,W]

    // Workspace layout (floats)
    float* ws    = (float*)d_ws;
    float* ze    = ws;                                  // N*64      (4 MB)
    float* hn    = ze    + (size_t)N_ * D_;             // K         (32 KB)
    float* pbest = hn    + K_;                          // CS*N      (1 MB)
    float* Vm    = pbest + (size_t)CS * N_;             // N         (64 KB)
    int*   cnt   = (int*)(Vm + N_);                     // N         (64 KB)
    int*   cand  = cnt + N_;                            // N*32      (2 MB)
    float* bsum  = (float*)(cand + (size_t)N_ * CAND_CAP); // 64

    k_proj <<<N_ / 64, 256, 0, stream>>>(z, pw, pb, gamma, beta, rmean, rvar, ze);
    k_hnorm<<<(K_ * D_ / 4) / 256, 256, 0, stream>>>(embed, hn);
    k_sweep<false><<<dim3(N_ / ROWS_PB, CS), 256, 0, stream>>>(
        ze, embed, hn, pbest, nullptr, nullptr, nullptr);
    k_comb <<<N_ / 256, 256, 0, stream>>>(pbest, Vm, cnt);
    k_sweep<true><<<dim3(N_ / ROWS_PB, CS), 256, 0, stream>>>(
        ze, embed, hn, pbest, Vm, cnt, cand);
    k_pick <<<N_ / 256, 256, 0, stream>>>(cnt, cand, embed, hn, ze, out0, outIdx, bsum);
    k_diff <<<1, 64, 0, stream>>>(bsum, outDiff);
}

// Round 5
// 198.340 us; speedup vs baseline: 37.5387x; 37.5387x over previous
//
#include <hip/hip_runtime.h>
#include <math.h>

// Problem constants
#define B_   16
#define C_   128
#define H_   32
#define W_   32
#define D_   64
#define K_   8192
#define HW_  (H_*W_)       // 1024
#define N_   (B_*HW_)      // 16384

// MFMA sweep config
#define CS      16         // code splits (grid.y)
#define CPB     (K_/CS)    // 512 codes per block
#define CHUNK   128        // codes per LDS chunk
#define ROWS_PB 256        // rows per block (4 waves x 64 rows)
// Worst-case bf16 screen error: 2^-7 * ||z|| * ||e|| <= 0.091 (hard C-S bound
// over actual norm tails). 0.12 > worst case; E[cands/row] ~ 1.9.
#define MARGIN  0.12f
#define CAND_CAP 32

typedef short v8s __attribute__((ext_vector_type(8)));
typedef float v4f __attribute__((ext_vector_type(4)));

__device__ __forceinline__ short f2bf(float f) {   // RNE fp32 -> bf16
    union { float fv; unsigned u; } cv; cv.fv = f;
    unsigned u = cv.u;
    unsigned rnd = ((u >> 16) & 1u) + 0x7fffu;
    return (short)((u + rnd) >> 16);
}

// Exact fp32 score, bit-identical to the R2 kernel that matched the reference:
// even/odd d4 interleave into two accumulators, then (sa+sb) - hn.
__device__ __forceinline__ float exact_score(const float4* __restrict__ zr,
                                             const float* __restrict__ embed,
                                             float h, int k)
{
    const float4* ep = (const float4*)(embed + (size_t)k * D_);
    float sa = 0.f, sb = 0.f;
    #pragma unroll
    for (int d4 = 0; d4 < 16; d4 += 2) {
        float4 ea = ep[d4], eb = ep[d4 + 1];
        sa += ea.x*zr[d4].x + ea.y*zr[d4].y + ea.z*zr[d4].z + ea.w*zr[d4].w;
        sb += eb.x*zr[d4+1].x + eb.y*zr[d4+1].y + eb.z*zr[d4+1].z + eb.w*zr[d4+1].w;
    }
    return (sa + sb) - h;
}

// ---------------- Kernel 1: 1x1 conv + BN -> z_e [N_, 64] ----------------
__global__ __launch_bounds__(256) void k_proj(
    const float* __restrict__ z, const float* __restrict__ pw,
    const float* __restrict__ pb, const float* __restrict__ gamma,
    const float* __restrict__ beta, const float* __restrict__ rmean,
    const float* __restrict__ rvar, float* __restrict__ ze)
{
    __shared__ float zt[64][132];
    __shared__ float wl[64][132];
    const int tid = threadIdx.x;
    const int n0  = blockIdx.x * 64;
    const int b   = n0 / HW_;
    const int hw0 = n0 % HW_;
    const float* zb = z + (size_t)b * C_ * HW_ + hw0;

    #pragma unroll
    for (int it = 0; it < 32; ++it) {
        int flat = tid + 256 * it;
        int c = flat >> 6, p = flat & 63;
        zt[p][c] = zb[c * HW_ + p];
    }
    #pragma unroll
    for (int it = 0; it < 32; ++it) {
        int flat = tid + 256 * it;
        int d = flat >> 7, c = flat & 127;
        wl[d][c] = pw[d * C_ + c];
    }
    __syncthreads();

    const int tp = tid & 15;
    const int td = tid >> 4;
    float acc[4][4] = {};
    #pragma unroll
    for (int c4 = 0; c4 < 32; ++c4) {
        float4 zv[4], wv[4];
        #pragma unroll
        for (int i = 0; i < 4; ++i) zv[i] = *(const float4*)&zt[4*tp + i][4*c4];
        #pragma unroll
        for (int j = 0; j < 4; ++j) wv[j] = *(const float4*)&wl[4*td + j][4*c4];
        #pragma unroll
        for (int i = 0; i < 4; ++i)
            #pragma unroll
            for (int j = 0; j < 4; ++j)
                acc[i][j] += zv[i].x*wv[j].x + zv[i].y*wv[j].y
                           + zv[i].z*wv[j].z + zv[i].w*wv[j].w;
    }

    float sc[4], bi[4];
    #pragma unroll
    for (int j = 0; j < 4; ++j) {
        int d = 4*td + j;
        float s = gamma[d] / sqrtf(rvar[d] + 1e-5f);
        sc[j] = s;
        bi[j] = pb[d] * s + beta[d] - rmean[d] * s;
    }
    #pragma unroll
    for (int i = 0; i < 4; ++i) {
        int n = n0 + 4*tp + i;
        float4 o;
        o.x = acc[i][0]*sc[0] + bi[0];
        o.y = acc[i][1]*sc[1] + bi[1];
        o.z = acc[i][2]*sc[2] + bi[2];
        o.w = acc[i][3]*sc[3] + bi[3];
        *(float4*)&ze[(size_t)n * D_ + 4*td] = o;
    }
}

// ---------------- Kernel 2: hn[k] = 0.5 * ||embed_k||^2 ----------------
__global__ __launch_bounds__(256) void k_hnorm(const float* __restrict__ e,
                                               float* __restrict__ hn)
{
    int t = blockIdx.x * 256 + threadIdx.x;
    float4 v = ((const float4*)e)[t];
    float s = v.x*v.x + v.y*v.y + v.z*v.z + v.w*v.w;
    s += __shfl_xor(s, 1);
    s += __shfl_xor(s, 2);
    s += __shfl_xor(s, 4);
    s += __shfl_xor(s, 8);
    if ((threadIdx.x & 15) == 0) hn[t >> 4] = 0.5f * s;
}

// ---------------- Kernel 3: MFMA bf16 sweep ----------------
template<bool PUSH>
__global__ __launch_bounds__(256) void k_sweep(
    const float* __restrict__ ze, const float* __restrict__ embed,
    const float* __restrict__ hn, float* __restrict__ pbest,
    const float* __restrict__ Vm, int* __restrict__ cnt,
    int* __restrict__ cand)
{
    __shared__ short eb[CHUNK * 72];   // 144B stride/code: b128 reads 2-way only
    __shared__ float hl[CHUNK];
    const int tid  = threadIdx.x;
    const int lane = tid & 63;
    const int wv   = tid >> 6;
    const int quad = lane >> 4;
    const int l15  = lane & 15;
    const int rowBase = blockIdx.x * ROWS_PB + wv * 64;
    const int code0   = blockIdx.y * CPB;

    // A fragments: 4 row-tiles x 2 k-frags; A[m=l15][k=quad*8+j] (+32 for f=1)
    v8s A[4][2];
    #pragma unroll
    for (int rt = 0; rt < 4; ++rt) {
        const float* zp = ze + (size_t)(rowBase + rt*16 + l15) * D_ + quad*8;
        #pragma unroll
        for (int f = 0; f < 2; ++f) {
            v8s a;
            #pragma unroll
            for (int j = 0; j < 8; ++j) a[j] = f2bf(zp[f*32 + j]);
            A[rt][f] = a;
        }
    }

    float best[4][4];
    float vm[4][4];
    if (PUSH) {
        #pragma unroll
        for (int rt = 0; rt < 4; ++rt)
            #pragma unroll
            for (int r = 0; r < 4; ++r)
                vm[rt][r] = Vm[rowBase + rt*16 + quad*4 + r];
    } else {
        #pragma unroll
        for (int rt = 0; rt < 4; ++rt)
            #pragma unroll
            for (int r = 0; r < 4; ++r) best[rt][r] = -INFINITY;
    }

    for (int ch = 0; ch < CPB / CHUNK; ++ch) {
        const int c0 = code0 + ch * CHUNK;
        __syncthreads();
        #pragma unroll
        for (int i = 0; i < 8; ++i) {
            int idx = tid + 256 * i;           // float4 units
            int c = idx >> 4, p = idx & 15;
            float4 v = ((const float4*)embed)[(size_t)(c0 + c) * 16 + p];
            short4 s4;
            s4.x = f2bf(v.x); s4.y = f2bf(v.y); s4.z = f2bf(v.z); s4.w = f2bf(v.w);
            *(short4*)&eb[c * 72 + p * 4] = s4;
        }
        if (tid < CHUNK) hl[tid] = hn[c0 + tid];
        __syncthreads();

        #pragma unroll
        for (int t = 0; t < CHUNK / 16; ++t) {
            const int cc = t * 16 + l15;
            v8s B0 = *(const v8s*)&eb[cc * 72 + quad * 8];        // d 0..31
            v8s B1 = *(const v8s*)&eb[cc * 72 + 32 + quad * 8];   // d 32..63
            const float mh = -hl[t * 16 + l15];
            #pragma unroll
            for (int rt = 0; rt < 4; ++rt) {
                v4f c = {mh, mh, mh, mh};
                c = __builtin_amdgcn_mfma_f32_16x16x32_bf16(A[rt][0], B0, c, 0, 0, 0);
                c = __builtin_amdgcn_mfma_f32_16x16x32_bf16(A[rt][1], B1, c, 0, 0, 0);
                if (!PUSH) {
                    #pragma unroll
                    for (int r = 0; r < 4; ++r) best[rt][r] = fmaxf(best[rt][r], c[r]);
                } else {
                    const int code = c0 + t * 16 + l15;
                    #pragma unroll
                    for (int r = 0; r < 4; ++r) {
                        if (c[r] > vm[rt][r]) {
                            int row = rowBase + rt*16 + quad*4 + r;
                            int s = atomicAdd(&cnt[row], 1);
                            if (s < CAND_CAP) cand[row * CAND_CAP + s] = code;
                        }
                    }
                }
            }
        }
    }

    if (!PUSH) {
        #pragma unroll
        for (int rt = 0; rt < 4; ++rt)
            #pragma unroll
            for (int r = 0; r < 4; ++r) {
                float v = best[rt][r];
                v = fmaxf(v, __shfl_xor(v, 1));
                v = fmaxf(v, __shfl_xor(v, 2));
                v = fmaxf(v, __shfl_xor(v, 4));
                v = fmaxf(v, __shfl_xor(v, 8));
                if (l15 == 0)
                    pbest[(size_t)blockIdx.y * N_ + rowBase + rt*16 + quad*4 + r] = v;
            }
    }
}

// ---------------- Kernel 4: combine splits -> threshold, zero counters ----
__global__ __launch_bounds__(256) void k_comb(const float* __restrict__ pbest,
                                              float* __restrict__ Vm,
                                              int* __restrict__ cnt)
{
    int n = blockIdx.x * 256 + threadIdx.x;
    float v = -INFINITY;
    #pragma unroll
    for (int s = 0; s < CS; ++s) v = fmaxf(v, pbest[(size_t)s * N_ + n]);
    Vm[n] = v - MARGIN;
    cnt[n] = 0;
}

// ---------------- Kernel 5: exact fp32 rescore + outputs ----------------
__global__ __launch_bounds__(256) void k_pick(
    const int* __restrict__ cnt, const int* __restrict__ cand,
    const float* __restrict__ embed, const float* __restrict__ hn,
    const float* __restrict__ ze, float* __restrict__ out0,
    float* __restrict__ outIdx, float* __restrict__ bsum)
{
    const int tid = threadIdx.x;
    const int n   = blockIdx.x * 256 + tid;

    float4 zr[16];
    const float4* zp = (const float4*)(ze + (size_t)n * D_);
    #pragma unroll
    for (int i = 0; i < 16; ++i) zr[i] = zp[i];

    const int m = cnt[n];
    float best = -INFINITY;
    int   bidx = 0x7fffffff;
    if (m > CAND_CAP) {
        // overflow fallback: full exact scan, ascending k (replicates R2 exactly)
        for (int k = 0; k < K_; ++k) {
            float s = exact_score(zr, embed, hn[k], k);
            if (s > best) { best = s; bidx = k; }
        }
    } else {
        for (int i = 0; i < m; ++i) {
            int k = cand[n * CAND_CAP + i];
            float s = exact_score(zr, embed, hn[k], k);
            // candidates arrive unordered: (s==best && k<bidx) == ascending strict->
            if (s > best || (s == best && k < bidx)) { best = s; bidx = k; }
        }
    }
    if (bidx == 0x7fffffff) bidx = 0;   // unreachable safety
    outIdx[n] = (float)bidx;

    const float4* eq = (const float4*)(embed + (size_t)bidx * D_);
    const int b = n >> 10, hw = n & 1023;
    float* o = out0 + (size_t)b * (D_ * HW_) + hw;

    float local = 0.f;
    #pragma unroll
    for (int d4 = 0; d4 < 16; ++d4) {
        float4 e = eq[d4], zv = zr[d4];
        float dx = e.x - zv.x, dy = e.y - zv.y, dz = e.z - zv.z, dw = e.w - zv.w;
        local += dx*dx + dy*dy + dz*dz + dw*dw;
        o[(4*d4 + 0) * HW_] = e.x;
        o[(4*d4 + 1) * HW_] = e.y;
        o[(4*d4 + 2) * HW_] = e.z;
        o[(4*d4 + 3) * HW_] = e.w;
    }

    __shared__ float red[256];
    red[tid] = local;
    __syncthreads();
    for (int s = 128; s > 0; s >>= 1) {
        if (tid < s) red[tid] += red[tid + s];
        __syncthreads();
    }
    if (tid == 0) bsum[blockIdx.x] = red[0];
}

// ---------------- Kernel 6: diff scalar ----------------
__global__ void k_diff(const float* __restrict__ bsum, float* __restrict__ outd)
{
    float s = bsum[threadIdx.x];
    s += __shfl_xor(s, 1);
    s += __shfl_xor(s, 2);
    s += __shfl_xor(s, 4);
    s += __shfl_xor(s, 8);
    s += __shfl_xor(s, 16);
    s += __shfl_xor(s, 32);
    if (threadIdx.x == 0) *outd = s * (12.5f / (float)(N_ * D_));
}

extern "C" void kernel_launch(void* const* d_in, const int* in_sizes, int n_in,
                              void* d_out, int out_size, void* d_ws, size_t ws_size,
                              hipStream_t stream)
{
    const float* z     = (const float*)d_in[0];
    const float* pw    = (const float*)d_in[1];
    const float* pb    = (const float*)d_in[2];
    const float* gamma = (const float*)d_in[3];
    const float* beta  = (const float*)d_in[4];
    const float* rmean = (const float*)d_in[5];
    const float* rvar  = (const float*)d_in[6];
    const float* embed = (const float*)d_in[7];

    float* out = (float*)d_out;
    float* out0    = out;                     // [B,D,H,W]
    float* outDiff = out + (size_t)N_ * D_;   // scalar
    float* outIdx  = outDiff + 1;             // [B,H,W]

    // Workspace layout (floats)
    float* ws    = (float*)d_ws;
    float* ze    = ws;                                  // N*64      (4 MB)
    float* hn    = ze    + (size_t)N_ * D_;             // K         (32 KB)
    float* pbest = hn    + K_;                          // CS*N      (1 MB)
    float* Vm    = pbest + (size_t)CS * N_;             // N         (64 KB)
    int*   cnt   = (int*)(Vm + N_);                     // N         (64 KB)
    int*   cand  = cnt + N_;                            // N*32      (2 MB)
    float* bsum  = (float*)(cand + (size_t)N_ * CAND_CAP); // 64

    k_proj <<<N_ / 64, 256, 0, stream>>>(z, pw, pb, gamma, beta, rmean, rvar, ze);
    k_hnorm<<<(K_ * D_ / 4) / 256, 256, 0, stream>>>(embed, hn);
    k_sweep<false><<<dim3(N_ / ROWS_PB, CS), 256, 0, stream>>>(
        ze, embed, hn, pbest, nullptr, nullptr, nullptr);
    k_comb <<<N_ / 256, 256, 0, stream>>>(pbest, Vm, cnt);
    k_sweep<true><<<dim3(N_ / ROWS_PB, CS), 256, 0, stream>>>(
        ze, embed, hn, pbest, Vm, cnt, cand);
    k_pick <<<N_ / 256, 256, 0, stream>>>(cnt, cand, embed, hn, ze, out0, outIdx, bsum);
    k_diff <<<1, 64, 0, stream>>>(bsum, outDiff);
}

// Round 7
// 196.556 us; speedup vs baseline: 37.8793x; 1.0091x over previous
//
#include <hip/hip_runtime.h>
#include <math.h>

// Problem constants
#define B_   16
#define C_   128
#define H_   32
#define W_   32
#define D_   64
#define K_   8192
#define HW_  (H_*W_)       // 1024
#define N_   (B_*HW_)      // 16384

// MFMA sweep config
#define CS      16         // code splits (grid.y)
#define CPB     (K_/CS)    // 512 codes per block
#define CHUNK   128        // codes per LDS chunk
#define NCH     (CPB/CHUNK)
#define ROWS_PB 256        // rows per block (4 waves x 64 rows)
// Worst-case bf16 screen error: 2^-7 * ||z|| * ||e|| <= 0.091 (hard C-S bound
// over actual norm tails). 0.12 > worst case; E[cands/row] ~ 1.9 (R5-verified).
#define MARGIN  0.12f
#define CAND_CAP 32

typedef short v8s __attribute__((ext_vector_type(8)));
typedef float v4f __attribute__((ext_vector_type(4)));

__device__ __forceinline__ short f2bf(float f) {   // RNE fp32 -> bf16
    union { float fv; unsigned u; } cv; cv.fv = f;
    unsigned u = cv.u;
    unsigned rnd = ((u >> 16) & 1u) + 0x7fffu;
    return (short)((u + rnd) >> 16);
}

// async 16B global->LDS (gfx950). Per-wave: uniform base + lane*16.
#define GLOAD_LDS16(gp, lp) __builtin_amdgcn_global_load_lds( \
    (const __attribute__((address_space(1))) unsigned int*)(gp), \
    (__attribute__((address_space(3))) unsigned int*)(lp), 16, 0, 0)

// Exact fp32 score, bit-identical to the R2 kernel that matched the reference.
__device__ __forceinline__ float exact_score(const float4* __restrict__ zr,
                                             const float* __restrict__ embed,
                                             float h, int k)
{
    const float4* ep = (const float4*)(embed + (size_t)k * D_);
    float sa = 0.f, sb = 0.f;
    #pragma unroll
    for (int d4 = 0; d4 < 16; d4 += 2) {
        float4 ea = ep[d4], eb = ep[d4 + 1];
        sa += ea.x*zr[d4].x + ea.y*zr[d4].y + ea.z*zr[d4].z + ea.w*zr[d4].w;
        sb += eb.x*zr[d4+1].x + eb.y*zr[d4+1].y + eb.z*zr[d4+1].z + eb.w*zr[d4+1].w;
    }
    return (sa + sb) - h;
}

// ---------------- Kernel 1: 1x1 conv + BN -> z_e fp32 + zbf bf16 ----------
__global__ __launch_bounds__(256) void k_proj(
    const float* __restrict__ z, const float* __restrict__ pw,
    const float* __restrict__ pb, const float* __restrict__ gamma,
    const float* __restrict__ beta, const float* __restrict__ rmean,
    const float* __restrict__ rvar, float* __restrict__ ze,
    short* __restrict__ zbf)
{
    __shared__ float zt[64][132];
    __shared__ float wl[64][132];
    const int tid = threadIdx.x;
    const int n0  = blockIdx.x * 64;
    const int b   = n0 / HW_;
    const int hw0 = n0 % HW_;
    const float* zb = z + (size_t)b * C_ * HW_ + hw0;

    #pragma unroll
    for (int it = 0; it < 32; ++it) {
        int flat = tid + 256 * it;
        int c = flat >> 6, p = flat & 63;
        zt[p][c] = zb[c * HW_ + p];
    }
    #pragma unroll
    for (int it = 0; it < 32; ++it) {
        int flat = tid + 256 * it;
        int d = flat >> 7, c = flat & 127;
        wl[d][c] = pw[d * C_ + c];
    }
    __syncthreads();

    const int tp = tid & 15;
    const int td = tid >> 4;
    float acc[4][4] = {};
    #pragma unroll
    for (int c4 = 0; c4 < 32; ++c4) {
        float4 zv[4], wv[4];
        #pragma unroll
        for (int i = 0; i < 4; ++i) zv[i] = *(const float4*)&zt[4*tp + i][4*c4];
        #pragma unroll
        for (int j = 0; j < 4; ++j) wv[j] = *(const float4*)&wl[4*td + j][4*c4];
        #pragma unroll
        for (int i = 0; i < 4; ++i)
            #pragma unroll
            for (int j = 0; j < 4; ++j)
                acc[i][j] += zv[i].x*wv[j].x + zv[i].y*wv[j].y
                           + zv[i].z*wv[j].z + zv[i].w*wv[j].w;
    }

    float sc[4], bi[4];
    #pragma unroll
    for (int j = 0; j < 4; ++j) {
        int d = 4*td + j;
        float s = gamma[d] / sqrtf(rvar[d] + 1e-5f);
        sc[j] = s;
        bi[j] = pb[d] * s + beta[d] - rmean[d] * s;
    }
    #pragma unroll
    for (int i = 0; i < 4; ++i) {
        int n = n0 + 4*tp + i;
        float4 o;
        o.x = acc[i][0]*sc[0] + bi[0];
        o.y = acc[i][1]*sc[1] + bi[1];
        o.z = acc[i][2]*sc[2] + bi[2];
        o.w = acc[i][3]*sc[3] + bi[3];
        *(float4*)&ze[(size_t)n * D_ + 4*td] = o;
        short4 ob;
        ob.x = f2bf(o.x); ob.y = f2bf(o.y); ob.z = f2bf(o.z); ob.w = f2bf(o.w);
        *(short4*)&zbf[(size_t)n * D_ + 4*td] = ob;
    }
}

// ---------------- Kernel 2: hn (tree IDENTICAL to R2/R5) + swizzled bf16 embed
// ebs layout: code k, 16B-chunk slot p holds original chunk j = p ^ (k&7).
__global__ __launch_bounds__(256) void k_prep(const float* __restrict__ e,
                                              float* __restrict__ hn,
                                              short* __restrict__ ebs)
{
    int t = blockIdx.x * 256 + threadIdx.x;      // K_*16 threads
    float4 v = ((const float4*)e)[t];
    float s = v.x*v.x + v.y*v.y + v.z*v.z + v.w*v.w;
    s += __shfl_xor(s, 1);
    s += __shfl_xor(s, 2);
    s += __shfl_xor(s, 4);
    s += __shfl_xor(s, 8);
    if ((threadIdx.x & 15) == 0) hn[t >> 4] = 0.5f * s;

    const int k = t >> 4, p = t & 15;
    if (p < 8) {
        const int j = p ^ (k & 7);
        const float* src = e + (size_t)k * D_ + j * 8;
        v8s o;
        #pragma unroll
        for (int i = 0; i < 8; ++i) o[i] = f2bf(src[i]);
        *(v8s*)(ebs + (size_t)k * D_ + p * 8) = o;
    }
}

// ---------------- Kernel 3: MFMA bf16 sweep (async-staged, swizzled) -------
template<bool PUSH>
__global__ __launch_bounds__(256) void k_sweep(
    const short* __restrict__ zbf, const short* __restrict__ ebs,
    const float* __restrict__ hn, float* __restrict__ pbest,
    const float* __restrict__ Vm, int* __restrict__ cnt,
    int* __restrict__ cand)
{
    __shared__ short eb[2][CHUNK * 64];   // 2 x 16 KB, swizzled image of ebs
    __shared__ float hl[2][CHUNK];
    const int tid  = threadIdx.x;
    const int lane = tid & 63;
    const int wv   = tid >> 6;
    const int q    = lane >> 4;
    const int l15  = lane & 15;
    const int m8   = l15 & 7;             // == (local code)&7 for this lane
    const int rowBase = blockIdx.x * ROWS_PB + wv * 64;
    const int code0   = blockIdx.y * CPB;

    // A fragments straight from pre-converted zbf: A[m=l15][k=f*32+q*8+j]
    v8s A[4][2];
    #pragma unroll
    for (int rt = 0; rt < 4; ++rt)
        #pragma unroll
        for (int f = 0; f < 2; ++f)
            A[rt][f] = *(const v8s*)(zbf + (size_t)(rowBase + rt*16 + l15) * D_
                                      + f*32 + q*8);

    float best[4][4];
    float vm[4][4];
    if (PUSH) {
        #pragma unroll
        for (int rt = 0; rt < 4; ++rt)
            #pragma unroll
            for (int r = 0; r < 4; ++r)
                vm[rt][r] = Vm[rowBase + rt*16 + q*4 + r];
    } else {
        #pragma unroll
        for (int rt = 0; rt < 4; ++rt)
            #pragma unroll
            for (int r = 0; r < 4; ++r) best[rt][r] = -INFINITY;
    }

    // lane-constant swizzled LDS read offsets (shorts):
    // B0 (d 0..31) needs chunk j=q  -> slot q^m8 ; B1 (d 32..63) j=q^4 -> slot (q^m8)^4
    const int rb0 = l15 * 64 + ((q ^ m8) * 8);
    const int rb1 = l15 * 64 + (((q ^ m8) ^ 4) * 8);

    const char* srcBase = (const char*)(ebs + (size_t)code0 * 64);
    #define STAGE(b, ch) do {                                              \
        const char* s_ = srcBase + (size_t)(ch) * (CHUNK * 128);           \
        char* l_ = (char*)&eb[(b)][0];                                     \
        _Pragma("unroll")                                                  \
        for (int i_ = 0; i_ < 4; ++i_) {                                   \
            int seg_ = (wv * 4 + i_) * 1024 + lane * 16;                   \
            GLOAD_LDS16(s_ + seg_, l_ + seg_);                             \
        }                                                                  \
        if (tid < CHUNK) hl[(b)][tid] = hn[code0 + (ch) * CHUNK + tid];    \
    } while (0)

    STAGE(0, 0);
    __syncthreads();

    #pragma unroll
    for (int ch = 0; ch < NCH; ++ch) {
        const int buf = ch & 1;
        if (ch + 1 < NCH) STAGE(buf ^ 1, ch + 1);
        const int c0 = code0 + ch * CHUNK;
        const short* ep = &eb[buf][0];

        #pragma unroll
        for (int t = 0; t < CHUNK / 16; ++t) {
            v8s B0 = *(const v8s*)(ep + rb0 + t * 1024);
            v8s B1 = *(const v8s*)(ep + rb1 + t * 1024);
            const float mh = -hl[buf][t * 16 + l15];
            #pragma unroll
            for (int rt = 0; rt < 4; ++rt) {
                v4f c = {mh, mh, mh, mh};
                c = __builtin_amdgcn_mfma_f32_16x16x32_bf16(A[rt][0], B0, c, 0, 0, 0);
                c = __builtin_amdgcn_mfma_f32_16x16x32_bf16(A[rt][1], B1, c, 0, 0, 0);
                if (!PUSH) {
                    #pragma unroll
                    for (int r = 0; r < 4; ++r) best[rt][r] = fmaxf(best[rt][r], c[r]);
                } else {
                    const int code = c0 + t * 16 + l15;
                    #pragma unroll
                    for (int r = 0; r < 4; ++r) {
                        if (c[r] > vm[rt][r]) {
                            int row = rowBase + rt*16 + q*4 + r;
                            int s = atomicAdd(&cnt[row], 1);
                            if (s < CAND_CAP) cand[row * CAND_CAP + s] = code;
                        }
                    }
                }
            }
        }
        __syncthreads();
    }
    #undef STAGE

    if (!PUSH) {
        #pragma unroll
        for (int rt = 0; rt < 4; ++rt)
            #pragma unroll
            for (int r = 0; r < 4; ++r) {
                float v = best[rt][r];
                v = fmaxf(v, __shfl_xor(v, 1));
                v = fmaxf(v, __shfl_xor(v, 2));
                v = fmaxf(v, __shfl_xor(v, 4));
                v = fmaxf(v, __shfl_xor(v, 8));
                if (l15 == 0)
                    pbest[(size_t)blockIdx.y * N_ + rowBase + rt*16 + q*4 + r] = v;
            }
    }
}

// ---------------- Kernel 4: combine splits -> threshold, zero counters ----
__global__ __launch_bounds__(256) void k_comb(const float* __restrict__ pbest,
                                              float* __restrict__ Vm,
                                              int* __restrict__ cnt)
{
    int n = blockIdx.x * 256 + threadIdx.x;
    float v = -INFINITY;
    #pragma unroll
    for (int s = 0; s < CS; ++s) v = fmaxf(v, pbest[(size_t)s * N_ + n]);
    Vm[n] = v - MARGIN;
    cnt[n] = 0;
}

// ---------------- Kernel 5: exact fp32 rescore + outputs ----------------
__global__ __launch_bounds__(256) void k_pick(
    const int* __restrict__ cnt, const int* __restrict__ cand,
    const float* __restrict__ embed, const float* __restrict__ hn,
    const float* __restrict__ ze, float* __restrict__ out0,
    float* __restrict__ outIdx, float* __restrict__ bsum)
{
    const int tid = threadIdx.x;
    const int n   = blockIdx.x * 256 + tid;

    float4 zr[16];
    const float4* zp = (const float4*)(ze + (size_t)n * D_);
    #pragma unroll
    for (int i = 0; i < 16; ++i) zr[i] = zp[i];

    const int m = cnt[n];
    float best = -INFINITY;
    int   bidx = 0x7fffffff;
    if (m > CAND_CAP) {
        for (int k = 0; k < K_; ++k) {
            float s = exact_score(zr, embed, hn[k], k);
            if (s > best) { best = s; bidx = k; }
        }
    } else {
        for (int i = 0; i < m; ++i) {
            int k = cand[n * CAND_CAP + i];
            float s = exact_score(zr, embed, hn[k], k);
            if (s > best || (s == best && k < bidx)) { best = s; bidx = k; }
        }
    }
    if (bidx == 0x7fffffff) bidx = 0;
    outIdx[n] = (float)bidx;

    const float4* eq = (const float4*)(embed + (size_t)bidx * D_);
    const int b = n >> 10, hw = n & 1023;
    float* o = out0 + (size_t)b * (D_ * HW_) + hw;

    float local = 0.f;
    #pragma unroll
    for (int d4 = 0; d4 < 16; ++d4) {
        float4 e = eq[d4], zv = zr[d4];
        float dx = e.x - zv.x, dy = e.y - zv.y, dz = e.z - zv.z, dw = e.w - zv.w;
        local += dx*dx + dy*dy + dz*dz + dw*dw;
        o[(4*d4 + 0) * HW_] = e.x;
        o[(4*d4 + 1) * HW_] = e.y;
        o[(4*d4 + 2) * HW_] = e.z;
        o[(4*d4 + 3) * HW_] = e.w;
    }

    __shared__ float red[256];
    red[tid] = local;
    __syncthreads();
    for (int s = 128; s > 0; s >>= 1) {
        if (tid < s) red[tid] += red[tid + s];
        __syncthreads();
    }
    if (tid == 0) bsum[blockIdx.x] = red[0];
}

// ---------------- Kernel 6: diff scalar ----------------
__global__ void k_diff(const float* __restrict__ bsum, float* __restrict__ outd)
{
    float s = bsum[threadIdx.x];
    s += __shfl_xor(s, 1);
    s += __shfl_xor(s, 2);
    s += __shfl_xor(s, 4);
    s += __shfl_xor(s, 8);
    s += __shfl_xor(s, 16);
    s += __shfl_xor(s, 32);
    if (threadIdx.x == 0) *outd = s * (12.5f / (float)(N_ * D_));
}

extern "C" void kernel_launch(void* const* d_in, const int* in_sizes, int n_in,
                              void* d_out, int out_size, void* d_ws, size_t ws_size,
                              hipStream_t stream)
{
    const float* z     = (const float*)d_in[0];
    const float* pw    = (const float*)d_in[1];
    const float* pb    = (const float*)d_in[2];
    const float* gamma = (const float*)d_in[3];
    const float* beta  = (const float*)d_in[4];
    const float* rmean = (const float*)d_in[5];
    const float* rvar  = (const float*)d_in[6];
    const float* embed = (const float*)d_in[7];

    float* out = (float*)d_out;
    float* out0    = out;                     // [B,D,H,W]
    float* outDiff = out + (size_t)N_ * D_;   // scalar
    float* outIdx  = outDiff + 1;             // [B,H,W]

    // Workspace layout
    float* ws    = (float*)d_ws;
    float* ze    = ws;                                   // N*64 f   (4 MB)
    short* zbf   = (short*)(ze + (size_t)N_ * D_);       // N*64 s   (2 MB)
    short* ebs   = zbf + (size_t)N_ * D_;                // K*64 s   (1 MB)
    float* hn    = (float*)(ebs + (size_t)K_ * D_);      // K        (32 KB)
    float* pbest = hn + K_;                              // CS*N     (1 MB)
    float* Vm    = pbest + (size_t)CS * N_;              // N        (64 KB)
    int*   cnt   = (int*)(Vm + N_);                      // N        (64 KB)
    int*   cand  = cnt + N_;                             // N*32     (2 MB)
    float* bsum  = (float*)(cand + (size_t)N_ * CAND_CAP); // 64

    k_proj <<<N_ / 64, 256, 0, stream>>>(z, pw, pb, gamma, beta, rmean, rvar, ze, zbf);
    k_prep <<<(K_ * 16) / 256, 256, 0, stream>>>(embed, hn, ebs);
    k_sweep<false><<<dim3(N_ / ROWS_PB, CS), 256, 0, stream>>>(
        zbf, ebs, hn, pbest, nullptr, nullptr, nullptr);
    k_comb <<<N_ / 256, 256, 0, stream>>>(pbest, Vm, cnt);
    k_sweep<true><<<dim3(N_ / ROWS_PB, CS), 256, 0, stream>>>(
        zbf, ebs, hn, pbest, Vm, cnt, cand);
    k_pick <<<N_ / 256, 256, 0, stream>>>(cnt, cand, embed, hn, ze, out0, outIdx, bsum);
    k_diff <<<1, 64, 0, stream>>>(bsum, outDiff);
}

// Round 8
// 170.434 us; speedup vs baseline: 43.6849x; 1.1533x over previous
//
#include <hip/hip_runtime.h>
#include <math.h>

// Problem constants
#define B_   16
#define C_   128
#define H_   32
#define W_   32
#define D_   64
#define K_   8192
#define HW_  (H_*W_)       // 1024
#define N_   (B_*HW_)      // 16384

// MFMA sweep config
#define CS      16         // code splits (grid.y)
#define CPB     (K_/CS)    // 512 codes per block
#define CHUNK   128        // codes per LDS chunk
#define NCH     (CPB/CHUNK)
#define ROWS_PB 256        // rows per block (4 waves x 64 rows)
// Worst-case bf16 screen error: 2^-7 * ||z|| * ||e|| <= 0.091 (hard C-S bound
// over actual norm tails). 0.12 > worst case; E[cands/row] ~ 1.9 (R5-verified).
#define MARGIN  0.12f
#define CAND_CAP 32

typedef short v8s __attribute__((ext_vector_type(8)));
typedef float v4f __attribute__((ext_vector_type(4)));

__device__ __forceinline__ short f2bf(float f) {   // RNE fp32 -> bf16
    union { float fv; unsigned u; } cv; cv.fv = f;
    unsigned u = cv.u;
    unsigned rnd = ((u >> 16) & 1u) + 0x7fffu;
    return (short)((u + rnd) >> 16);
}

// async 16B global->LDS (gfx950). Per-wave: uniform base + lane*16.
#define GLOAD_LDS16(gp, lp) __builtin_amdgcn_global_load_lds( \
    (const __attribute__((address_space(1))) unsigned int*)(gp), \
    (__attribute__((address_space(3))) unsigned int*)(lp), 16, 0, 0)

// Exact fp32 score, bit-identical to the R2 kernel that matched the reference.
__device__ __forceinline__ float exact_score(const float4* __restrict__ zr,
                                             const float* __restrict__ embed,
                                             float h, int k)
{
    const float4* ep = (const float4*)(embed + (size_t)k * D_);
    float sa = 0.f, sb = 0.f;
    #pragma unroll
    for (int d4 = 0; d4 < 16; d4 += 2) {
        float4 ea = ep[d4], eb = ep[d4 + 1];
        sa += ea.x*zr[d4].x + ea.y*zr[d4].y + ea.z*zr[d4].z + ea.w*zr[d4].w;
        sb += eb.x*zr[d4+1].x + eb.y*zr[d4+1].y + eb.z*zr[d4+1].z + eb.w*zr[d4+1].w;
    }
    return (sa + sb) - h;
}

// ---------------- Kernel 1: 1x1 conv + BN -> z_e fp32 + zbf bf16 ----------
__global__ __launch_bounds__(256) void k_proj(
    const float* __restrict__ z, const float* __restrict__ pw,
    const float* __restrict__ pb, const float* __restrict__ gamma,
    const float* __restrict__ beta, const float* __restrict__ rmean,
    const float* __restrict__ rvar, float* __restrict__ ze,
    short* __restrict__ zbf)
{
    __shared__ float zt[64][132];
    __shared__ float wl[64][132];
    const int tid = threadIdx.x;
    const int n0  = blockIdx.x * 64;
    const int b   = n0 / HW_;
    const int hw0 = n0 % HW_;
    const float* zb = z + (size_t)b * C_ * HW_ + hw0;

    #pragma unroll
    for (int it = 0; it < 32; ++it) {
        int flat = tid + 256 * it;
        int c = flat >> 6, p = flat & 63;
        zt[p][c] = zb[c * HW_ + p];
    }
    #pragma unroll
    for (int it = 0; it < 32; ++it) {
        int flat = tid + 256 * it;
        int d = flat >> 7, c = flat & 127;
        wl[d][c] = pw[d * C_ + c];
    }
    __syncthreads();

    const int tp = tid & 15;
    const int td = tid >> 4;
    float acc[4][4] = {};
    #pragma unroll
    for (int c4 = 0; c4 < 32; ++c4) {
        float4 zv[4], wv[4];
        #pragma unroll
        for (int i = 0; i < 4; ++i) zv[i] = *(const float4*)&zt[4*tp + i][4*c4];
        #pragma unroll
        for (int j = 0; j < 4; ++j) wv[j] = *(const float4*)&wl[4*td + j][4*c4];
        #pragma unroll
        for (int i = 0; i < 4; ++i)
            #pragma unroll
            for (int j = 0; j < 4; ++j)
                acc[i][j] += zv[i].x*wv[j].x + zv[i].y*wv[j].y
                           + zv[i].z*wv[j].z + zv[i].w*wv[j].w;
    }

    float sc[4], bi[4];
    #pragma unroll
    for (int j = 0; j < 4; ++j) {
        int d = 4*td + j;
        float s = gamma[d] / sqrtf(rvar[d] + 1e-5f);
        sc[j] = s;
        bi[j] = pb[d] * s + beta[d] - rmean[d] * s;
    }
    #pragma unroll
    for (int i = 0; i < 4; ++i) {
        int n = n0 + 4*tp + i;
        float4 o;
        o.x = acc[i][0]*sc[0] + bi[0];
        o.y = acc[i][1]*sc[1] + bi[1];
        o.z = acc[i][2]*sc[2] + bi[2];
        o.w = acc[i][3]*sc[3] + bi[3];
        *(float4*)&ze[(size_t)n * D_ + 4*td] = o;
        short4 ob;
        ob.x = f2bf(o.x); ob.y = f2bf(o.y); ob.z = f2bf(o.z); ob.w = f2bf(o.w);
        *(short4*)&zbf[(size_t)n * D_ + 4*td] = ob;
    }
}

// ---------------- Kernel 2: hn (tree IDENTICAL to R2/R5) + swizzled bf16 embed
// ebs layout: code k, 16B-chunk slot p holds original chunk j = p ^ (k&7).
__global__ __launch_bounds__(256) void k_prep(const float* __restrict__ e,
                                              float* __restrict__ hn,
                                              short* __restrict__ ebs)
{
    int t = blockIdx.x * 256 + threadIdx.x;      // K_*16 threads
    float4 v = ((const float4*)e)[t];
    float s = v.x*v.x + v.y*v.y + v.z*v.z + v.w*v.w;
    s += __shfl_xor(s, 1);
    s += __shfl_xor(s, 2);
    s += __shfl_xor(s, 4);
    s += __shfl_xor(s, 8);
    if ((threadIdx.x & 15) == 0) hn[t >> 4] = 0.5f * s;

    const int k = t >> 4, p = t & 15;
    if (p < 8) {
        const int j = p ^ (k & 7);
        const float* src = e + (size_t)k * D_ + j * 8;
        v8s o;
        #pragma unroll
        for (int i = 0; i < 8; ++i) o[i] = f2bf(src[i]);
        *(v8s*)(ebs + (size_t)k * D_ + p * 8) = o;
    }
}

// ---------------- Kernel 3: MFMA bf16 sweep (async-staged, swizzled) -------
template<bool PUSH>
__global__ __launch_bounds__(256) void k_sweep(
    const short* __restrict__ zbf, const short* __restrict__ ebs,
    const float* __restrict__ hn, float* __restrict__ pbest,
    const float* __restrict__ Vm, int* __restrict__ cnt,
    int* __restrict__ cand)
{
    __shared__ short eb[2][CHUNK * 64];   // 2 x 16 KB, swizzled image of ebs
    __shared__ float hl[2][CHUNK];
    const int tid  = threadIdx.x;
    const int lane = tid & 63;
    const int wv   = tid >> 6;
    const int q    = lane >> 4;
    const int l15  = lane & 15;
    const int m8   = l15 & 7;             // == (local code)&7 for this lane
    const int rowBase = blockIdx.x * ROWS_PB + wv * 64;
    const int code0   = blockIdx.y * CPB;

    // A fragments straight from pre-converted zbf: A[m=l15][k=f*32+q*8+j]
    v8s A[4][2];
    #pragma unroll
    for (int rt = 0; rt < 4; ++rt)
        #pragma unroll
        for (int f = 0; f < 2; ++f)
            A[rt][f] = *(const v8s*)(zbf + (size_t)(rowBase + rt*16 + l15) * D_
                                      + f*32 + q*8);

    float best[4][4];
    float vm[4][4];
    if (PUSH) {
        #pragma unroll
        for (int rt = 0; rt < 4; ++rt)
            #pragma unroll
            for (int r = 0; r < 4; ++r)
                vm[rt][r] = Vm[rowBase + rt*16 + q*4 + r];
    } else {
        #pragma unroll
        for (int rt = 0; rt < 4; ++rt)
            #pragma unroll
            for (int r = 0; r < 4; ++r) best[rt][r] = -INFINITY;
    }

    // lane-constant swizzled LDS read offsets (shorts):
    // B0 (d 0..31) needs chunk j=q  -> slot q^m8 ; B1 (d 32..63) j=q^4 -> slot (q^m8)^4
    const int rb0 = l15 * 64 + ((q ^ m8) * 8);
    const int rb1 = l15 * 64 + (((q ^ m8) ^ 4) * 8);

    const char* srcBase = (const char*)(ebs + (size_t)code0 * 64);
    #define STAGE(b, ch) do {                                              \
        const char* s_ = srcBase + (size_t)(ch) * (CHUNK * 128);           \
        char* l_ = (char*)&eb[(b)][0];                                     \
        _Pragma("unroll")                                                  \
        for (int i_ = 0; i_ < 4; ++i_) {                                   \
            int seg_ = (wv * 4 + i_) * 1024 + lane * 16;                   \
            GLOAD_LDS16(s_ + seg_, l_ + seg_);                             \
        }                                                                  \
        if (tid < CHUNK) hl[(b)][tid] = hn[code0 + (ch) * CHUNK + tid];    \
    } while (0)

    STAGE(0, 0);
    __syncthreads();

    #pragma unroll 1   // keep body inside the 32 KB I$ (R7 lesson)
    for (int ch = 0; ch < NCH; ++ch) {
        const int buf = ch & 1;
        if (ch + 1 < NCH) STAGE(buf ^ 1, ch + 1);
        const int c0 = code0 + ch * CHUNK;
        const short* ep = &eb[buf][0];

        #pragma unroll
        for (int t = 0; t < CHUNK / 16; ++t) {
            v8s B0 = *(const v8s*)(ep + rb0 + t * 1024);
            v8s B1 = *(const v8s*)(ep + rb1 + t * 1024);
            const float mh = -hl[buf][t * 16 + l15];
            #pragma unroll
            for (int rt = 0; rt < 4; ++rt) {
                v4f c = {mh, mh, mh, mh};
                c = __builtin_amdgcn_mfma_f32_16x16x32_bf16(A[rt][0], B0, c, 0, 0, 0);
                c = __builtin_amdgcn_mfma_f32_16x16x32_bf16(A[rt][1], B1, c, 0, 0, 0);
                if (!PUSH) {
                    #pragma unroll
                    for (int r = 0; r < 4; ++r) best[rt][r] = fmaxf(best[rt][r], c[r]);
                } else {
                    // branchless per-value test, one guard branch per rt
                    bool a0 = c[0] > vm[rt][0];
                    bool a1 = c[1] > vm[rt][1];
                    bool a2 = c[2] > vm[rt][2];
                    bool a3 = c[3] > vm[rt][3];
                    if (a0 | a1 | a2 | a3) {
                        const int code = c0 + t * 16 + l15;
                        const int row0 = rowBase + rt*16 + q*4;
                        #pragma unroll
                        for (int r = 0; r < 4; ++r) {
                            if (c[r] > vm[rt][r]) {
                                int s = atomicAdd(&cnt[row0 + r], 1);
                                if (s < CAND_CAP) cand[(row0 + r) * CAND_CAP + s] = code;
                            }
                        }
                    }
                }
            }
        }
        __syncthreads();
    }
    #undef STAGE

    if (!PUSH) {
        #pragma unroll
        for (int rt = 0; rt < 4; ++rt)
            #pragma unroll
            for (int r = 0; r < 4; ++r) {
                float v = best[rt][r];
                v = fmaxf(v, __shfl_xor(v, 1));
                v = fmaxf(v, __shfl_xor(v, 2));
                v = fmaxf(v, __shfl_xor(v, 4));
                v = fmaxf(v, __shfl_xor(v, 8));
                if (l15 == 0)
                    pbest[(size_t)blockIdx.y * N_ + rowBase + rt*16 + q*4 + r] = v;
            }
    }
}

// ---------------- Kernel 4: combine splits -> threshold, zero counters ----
__global__ __launch_bounds__(256) void k_comb(const float* __restrict__ pbest,
                                              float* __restrict__ Vm,
                                              int* __restrict__ cnt)
{
    int n = blockIdx.x * 256 + threadIdx.x;
    float v = -INFINITY;
    #pragma unroll
    for (int s = 0; s < CS; ++s) v = fmaxf(v, pbest[(size_t)s * N_ + n]);
    Vm[n] = v - MARGIN;
    cnt[n] = 0;
}

// ---------------- Kernel 5: exact fp32 rescore + outputs ----------------
// 64-thread blocks x 256 blocks: full CU coverage (R7: 64-block grid = 25% CUs)
__global__ __launch_bounds__(64) void k_pick(
    const int* __restrict__ cnt, const int* __restrict__ cand,
    const float* __restrict__ embed, const float* __restrict__ hn,
    const float* __restrict__ ze, float* __restrict__ out0,
    float* __restrict__ outIdx, float* __restrict__ bsum)
{
    const int tid = threadIdx.x;
    const int n   = blockIdx.x * 64 + tid;

    float4 zr[16];
    const float4* zp = (const float4*)(ze + (size_t)n * D_);
    #pragma unroll
    for (int i = 0; i < 16; ++i) zr[i] = zp[i];

    const int m = cnt[n];
    float best = -INFINITY;
    int   bidx = 0x7fffffff;
    if (m > CAND_CAP) {
        for (int k = 0; k < K_; ++k) {
            float s = exact_score(zr, embed, hn[k], k);
            if (s > best) { best = s; bidx = k; }
        }
    } else {
        for (int i = 0; i < m; ++i) {
            int k = cand[n * CAND_CAP + i];
            float s = exact_score(zr, embed, hn[k], k);
            if (s > best || (s == best && k < bidx)) { best = s; bidx = k; }
        }
    }
    if (bidx == 0x7fffffff) bidx = 0;
    outIdx[n] = (float)bidx;

    const float4* eq = (const float4*)(embed + (size_t)bidx * D_);
    const int b = n >> 10, hw = n & 1023;
    float* o = out0 + (size_t)b * (D_ * HW_) + hw;

    float local = 0.f;
    #pragma unroll
    for (int d4 = 0; d4 < 16; ++d4) {
        float4 e = eq[d4], zv = zr[d4];
        float dx = e.x - zv.x, dy = e.y - zv.y, dz = e.z - zv.z, dw = e.w - zv.w;
        local += dx*dx + dy*dy + dz*dz + dw*dw;
        o[(4*d4 + 0) * HW_] = e.x;
        o[(4*d4 + 1) * HW_] = e.y;
        o[(4*d4 + 2) * HW_] = e.z;
        o[(4*d4 + 3) * HW_] = e.w;
    }

    // wave-level reduce (block == one wave)
    local += __shfl_xor(local, 1);
    local += __shfl_xor(local, 2);
    local += __shfl_xor(local, 4);
    local += __shfl_xor(local, 8);
    local += __shfl_xor(local, 16);
    local += __shfl_xor(local, 32);
    if (tid == 0) bsum[blockIdx.x] = local;
}

// ---------------- Kernel 6: diff scalar (256 partials) ----------------
__global__ __launch_bounds__(256) void k_diff(const float* __restrict__ bsum,
                                              float* __restrict__ outd)
{
    __shared__ float red[256];
    float s = bsum[threadIdx.x];
    red[threadIdx.x] = s;
    __syncthreads();
    for (int st = 128; st > 0; st >>= 1) {
        if (threadIdx.x < st) red[threadIdx.x] += red[threadIdx.x + st];
        __syncthreads();
    }
    if (threadIdx.x == 0) *outd = red[0] * (12.5f / (float)(N_ * D_));
}

extern "C" void kernel_launch(void* const* d_in, const int* in_sizes, int n_in,
                              void* d_out, int out_size, void* d_ws, size_t ws_size,
                              hipStream_t stream)
{
    const float* z     = (const float*)d_in[0];
    const float* pw    = (const float*)d_in[1];
    const float* pb    = (const float*)d_in[2];
    const float* gamma = (const float*)d_in[3];
    const float* beta  = (const float*)d_in[4];
    const float* rmean = (const float*)d_in[5];
    const float* rvar  = (const float*)d_in[6];
    const float* embed = (const float*)d_in[7];

    float* out = (float*)d_out;
    float* out0    = out;                     // [B,D,H,W]
    float* outDiff = out + (size_t)N_ * D_;   // scalar
    float* outIdx  = outDiff + 1;             // [B,H,W]

    // Workspace layout
    float* ws    = (float*)d_ws;
    float* ze    = ws;                                   // N*64 f   (4 MB)
    short* zbf   = (short*)(ze + (size_t)N_ * D_);       // N*64 s   (2 MB)
    short* ebs   = zbf + (size_t)N_ * D_;                // K*64 s   (1 MB)
    float* hn    = (float*)(ebs + (size_t)K_ * D_);      // K        (32 KB)
    float* pbest = hn + K_;                              // CS*N     (1 MB)
    float* Vm    = pbest + (size_t)CS * N_;              // N        (64 KB)
    int*   cnt   = (int*)(Vm + N_);                      // N        (64 KB)
    int*   cand  = cnt + N_;                             // N*32     (2 MB)
    float* bsum  = (float*)(cand + (size_t)N_ * CAND_CAP); // 256

    k_proj <<<N_ / 64, 256, 0, stream>>>(z, pw, pb, gamma, beta, rmean, rvar, ze, zbf);
    k_prep <<<(K_ * 16) / 256, 256, 0, stream>>>(embed, hn, ebs);
    k_sweep<false><<<dim3(N_ / ROWS_PB, CS), 256, 0, stream>>>(
        zbf, ebs, hn, pbest, nullptr, nullptr, nullptr);
    k_comb <<<N_ / 256, 256, 0, stream>>>(pbest, Vm, cnt);
    k_sweep<true><<<dim3(N_ / ROWS_PB, CS), 256, 0, stream>>>(
        zbf, ebs, hn, pbest, Vm, cnt, cand);
    k_pick <<<N_ / 64, 64, 0, stream>>>(cnt, cand, embed, hn, ze, out0, outIdx, bsum);
    k_diff <<<1, 256, 0, stream>>>(bsum, outDiff);
}